// Round 2
// baseline (604.712 us; speedup 1.0000x reference)
//
#include <hip/hip_runtime.h>
#include <hip/hip_bf16.h>
#include <cstdint>

#define HW 50176
#define CB 96
#define BATCH 4
#define NTOK (BATCH*HW)
#define NWIN 4096
#define HIDDEN 384

typedef __attribute__((ext_vector_type(8))) short bf16x8;
typedef __attribute__((ext_vector_type(4))) float f32x4;

__device__ inline unsigned short f2bf(float f){
  union { float f; unsigned u; } x; x.f = f;
  unsigned r = x.u + 0x7fffu + ((x.u >> 16) & 1u);
  return (unsigned short)(r >> 16);
}
__device__ inline float bf2f(unsigned short h){
  union { unsigned u; float f; } x; x.u = ((unsigned)h) << 16; return x.f;
}
__device__ inline unsigned pack2(float a, float b){
  return (unsigned)f2bf(a) | ((unsigned)f2bf(b) << 16);
}

// ---------------- weight prep: fp32 (K,N) -> bf16 transposed (N,K) ----------
__global__ void wprep(const float* __restrict__ src, unsigned short* __restrict__ dst,
                      int K, int N){
  int id = blockIdx.x * 256 + threadIdx.x;
  if (id >= K * N) return;
  int n = id / K, k = id - n * K;
  dst[id] = f2bf(src[k * N + n]);
}

// ---------------- LN1: NCHW -> token-major bf16, layernorm over C ----------
__global__ __launch_bounds__(256) void ln_first(const float* __restrict__ x,
    const float* __restrict__ g, const float* __restrict__ bta,
    unsigned short* __restrict__ out){
  __shared__ float s[64][97];
  int tid = threadIdx.x;
  int blk = blockIdx.x;
  int bi = blk / (HW / 64);
  int pos0 = (blk - bi * (HW / 64)) * 64;
  const float* xb = x + (size_t)bi * CB * HW + pos0;
  for (int it = 0; it < 24; ++it){
    int idx = it * 256 + tid;
    int c = idx >> 6, p = idx & 63;
    s[p][c] = xb[(size_t)c * HW + p];
  }
  __syncthreads();
  int p = tid >> 2, part = tid & 3;
  float sum = 0.f, sq = 0.f;
  #pragma unroll
  for (int j = 0; j < 24; ++j){ float v = s[p][part * 24 + j]; sum += v; sq += v * v; }
  sum += __shfl_xor(sum, 1); sq += __shfl_xor(sq, 1);
  sum += __shfl_xor(sum, 2); sq += __shfl_xor(sq, 2);
  float mean = sum * (1.f / 96.f);
  float var  = sq * (1.f / 96.f) - mean * mean;
  float rs = rsqrtf(var + 1e-5f);
  size_t tok = (size_t)bi * HW + pos0 + p;
  float vv[24];
  #pragma unroll
  for (int j = 0; j < 24; ++j){
    int c = part * 24 + j;
    vv[j] = (s[p][c] - mean) * rs * g[c] + bta[c];
  }
  unsigned pw[12];
  #pragma unroll
  for (int j = 0; j < 12; ++j) pw[j] = pack2(vv[2 * j], vv[2 * j + 1]);
  uint4* dst = (uint4*)(out + tok * CB + part * 24);
  dst[0] = make_uint4(pw[0], pw[1], pw[2], pw[3]);
  dst[1] = make_uint4(pw[4], pw[5], pw[6], pw[7]);
  dst[2] = make_uint4(pw[8], pw[9], pw[10], pw[11]);
}

// ---------------- fused qkv-GEMM + window attention (in-place on xn) -------
// block = 1 window (256 thr, 4 waves). GEMM: wave -> N-slice of qkv.
// attention: waves 0-2 = heads, lane (<49) = query row.
__global__ __launch_bounds__(256) void attn_fused(
    unsigned short* __restrict__ xn,           // in: xn1, out: attn_out
    const unsigned short* __restrict__ qkvT,   // (288,96) bf16
    const float* __restrict__ qkv_b,
    const float* __restrict__ rel_bias, const int* __restrict__ rel_index){
  __shared__ unsigned short sQ[49][104];       // bf16 Q rows
  __shared__ float sKV[49][200];               // [.,0..95]=K, [.,96..191]=V
  int tid = threadIdx.x;
  int wid = blockIdx.x;
  int bi = wid >> 10;
  int wy = (wid & 1023) >> 5, wx = wid & 31;
  int rowbase = bi * HW + (wy * 7) * 224 + wx * 7;   // + i*224 + j

  int wv = tid >> 6, lane = tid & 63;
  int r = lane & 15, kg = (lane >> 4) * 8;
  // qkv GEMM: wave wv handles ntiles {0-4,5-9,10-13,14-17}
  int nbase = (wv < 2) ? wv * 5 : 10 + (wv - 2) * 4;
  int ncnt  = (wv < 2) ? 5 : 4;
  int arow[4];
  #pragma unroll
  for (int m = 0; m < 4; ++m){
    int rr = m * 16 + r; if (rr > 48) rr = 48;
    arow[m] = rowbase + (rr / 7) * 224 + (rr % 7);
  }
  f32x4 acc[4][5];
  #pragma unroll
  for (int m = 0; m < 4; ++m)
    #pragma unroll
    for (int j = 0; j < 5; ++j) acc[m][j] = (f32x4){0.f,0.f,0.f,0.f};
  #pragma unroll
  for (int k0 = 0; k0 < 96; k0 += 32){
    bf16x8 a[4];
    #pragma unroll
    for (int m = 0; m < 4; ++m)
      a[m] = *(const bf16x8*)(xn + (size_t)arow[m] * CB + kg + k0);
    #pragma unroll
    for (int j = 0; j < 5; ++j){
      if (j < ncnt){
        int nt = nbase + j;
        bf16x8 b = *(const bf16x8*)(qkvT + (nt * 16 + r) * CB + kg + k0);
        #pragma unroll
        for (int m = 0; m < 4; ++m)
          acc[m][j] = __builtin_amdgcn_mfma_f32_16x16x32_bf16(a[m], b, acc[m][j], 0, 0, 0);
      }
    }
  }
  int orow = (lane >> 4) * 4;
  #pragma unroll
  for (int j = 0; j < 5; ++j){
    if (j < ncnt){
      int nt = nbase + j;
      int col = nt * 16 + r;
      float bs = qkv_b[col];
      #pragma unroll
      for (int m = 0; m < 4; ++m){
        #pragma unroll
        for (int i = 0; i < 4; ++i){
          int row = m * 16 + orow + i;
          if (row < 49){
            float v = acc[m][j][i] + bs;
            if (col < 96) sQ[row][col] = f2bf(v);
            else          sKV[row][col - 96] = v;
          }
        }
      }
    }
  }
  __syncthreads();

  if (wv < 3){
    int h = wv;
    int n = lane < 49 ? lane : 48;
    float q[32];
    {
      const uint4* qp = (const uint4*)&sQ[n][h * 32];
      #pragma unroll
      for (int c4 = 0; c4 < 4; ++c4){
        uint4 u = qp[c4];
        unsigned uu[4] = {u.x, u.y, u.z, u.w};
        #pragma unroll
        for (int q2 = 0; q2 < 4; ++q2){
          q[c4 * 8 + 2 * q2]     = bf2f((unsigned short)(uu[q2] & 0xffffu)) * 0.17677669529663687f;
          q[c4 * 8 + 2 * q2 + 1] = bf2f((unsigned short)(uu[q2] >> 16))     * 0.17677669529663687f;
        }
      }
    }
    float s[49];
    const int* ri = rel_index + n * 49;
    #pragma unroll
    for (int m = 0; m < 49; ++m) s[m] = rel_bias[ri[m] * 3 + h];
    #pragma unroll
    for (int m = 0; m < 49; ++m){
      float a = s[m];
      const float4* kr = (const float4*)&sKV[m][h * 32];
      #pragma unroll
      for (int c4 = 0; c4 < 8; ++c4){
        float4 kv = kr[c4];
        a += q[c4*4] * kv.x + q[c4*4+1] * kv.y + q[c4*4+2] * kv.z + q[c4*4+3] * kv.w;
      }
      s[m] = a;
    }
    float mx = -1e30f;
    #pragma unroll
    for (int m = 0; m < 49; ++m) mx = fmaxf(mx, s[m]);
    float sum = 0.f;
    #pragma unroll
    for (int m = 0; m < 49; ++m){ s[m] = __expf(s[m] - mx); sum += s[m]; }
    float inv = 1.f / sum;
    float o[32];
    #pragma unroll
    for (int d = 0; d < 32; ++d) o[d] = 0.f;
    #pragma unroll
    for (int m = 0; m < 49; ++m){
      float p = s[m];
      const float4* vr = (const float4*)&sKV[m][96 + h * 32];
      #pragma unroll
      for (int c4 = 0; c4 < 8; ++c4){
        float4 vvv = vr[c4];
        o[c4*4]   += p * vvv.x;  o[c4*4+1] += p * vvv.y;
        o[c4*4+2] += p * vvv.z;  o[c4*4+3] += p * vvv.w;
      }
    }
    if (lane < 49){
      int tok = rowbase + (n / 7) * 224 + (n % 7);
      unsigned pw[16];
      #pragma unroll
      for (int j = 0; j < 16; ++j) pw[j] = pack2(o[2*j] * inv, o[2*j+1] * inv);
      uint4* dst = (uint4*)(xn + (size_t)tok * CB + h * 32);
      #pragma unroll
      for (int c4 = 0; c4 < 4; ++c4)
        dst[c4] = make_uint4(pw[c4*4], pw[c4*4+1], pw[c4*4+2], pw[c4*4+3]);
    }
  }
}

// ---------------- proj GEMM + residual + LN2 (in-place att->xn2) -----------
__global__ __launch_bounds__(256) void proj_ln2(
    unsigned short* __restrict__ att,          // in: attn_out, out: xn2
    const unsigned short* __restrict__ projT, const float* __restrict__ proj_b,
    const float* __restrict__ x, const float* __restrict__ g,
    const float* __restrict__ bta,
    float* __restrict__ x2out){                // d_out, NCHW
  __shared__ float sY[64][101];
  int tid = threadIdx.x, blk = blockIdx.x;
  int bi = blk / (HW / 64);
  int pos0 = (blk - bi * (HW / 64)) * 64;
  size_t tokBase = (size_t)bi * HW + pos0;
  int wv = tid >> 6, lane = tid & 63;
  int r = lane & 15, kg = (lane >> 4) * 8;
  const unsigned short* Arow = att + (tokBase + wv * 16 + r) * CB + kg;
  f32x4 acc[6];
  #pragma unroll
  for (int j = 0; j < 6; ++j) acc[j] = (f32x4){0.f,0.f,0.f,0.f};
  #pragma unroll
  for (int k0 = 0; k0 < 96; k0 += 32){
    bf16x8 a = *(const bf16x8*)(Arow + k0);
    #pragma unroll
    for (int j = 0; j < 6; ++j){
      bf16x8 b = *(const bf16x8*)(projT + (j * 16 + r) * CB + kg + k0);
      acc[j] = __builtin_amdgcn_mfma_f32_16x16x32_bf16(a, b, acc[j], 0, 0, 0);
    }
  }
  int orow = wv * 16 + (lane >> 4) * 4;
  #pragma unroll
  for (int j = 0; j < 6; ++j){
    int col = j * 16 + r;
    float bs = proj_b[col];
    #pragma unroll
    for (int i = 0; i < 4; ++i) sY[orow + i][col] = acc[j][i] + bs;
  }
  __syncthreads();
  const float* xb = x + (size_t)bi * CB * HW + pos0;
  float* ob = x2out + (size_t)bi * CB * HW + pos0;
  for (int it = 0; it < 24; ++it){
    int idx = it * 256 + tid;
    int c = idx >> 6, p = idx & 63;
    float v = sY[p][c] + xb[(size_t)c * HW + p];
    ob[(size_t)c * HW + p] = v;
    sY[p][c] = v;
  }
  __syncthreads();
  int p = tid >> 2, part = tid & 3;
  float sum = 0.f, sq = 0.f;
  #pragma unroll
  for (int j = 0; j < 24; ++j){ float v = sY[p][part * 24 + j]; sum += v; sq += v * v; }
  sum += __shfl_xor(sum, 1); sq += __shfl_xor(sq, 1);
  sum += __shfl_xor(sum, 2); sq += __shfl_xor(sq, 2);
  float mean = sum * (1.f / 96.f);
  float var  = sq * (1.f / 96.f) - mean * mean;
  float rs = rsqrtf(var + 1e-5f);
  float vv[24];
  #pragma unroll
  for (int j = 0; j < 24; ++j){
    int c = part * 24 + j;
    vv[j] = (sY[p][c] - mean) * rs * g[c] + bta[c];
  }
  unsigned pw[12];
  #pragma unroll
  for (int j = 0; j < 12; ++j) pw[j] = pack2(vv[2 * j], vv[2 * j + 1]);
  uint4* dst = (uint4*)(att + (tokBase + p) * CB + part * 24);
  dst[0] = make_uint4(pw[0], pw[1], pw[2], pw[3]);
  dst[1] = make_uint4(pw[4], pw[5], pw[6], pw[7]);
  dst[2] = make_uint4(pw[8], pw[9], pw[10], pw[11]);
}

// ---------------- fused MLP: gelu(xn2@w1+b1)@w2+b2 + x2 -> out (NCHW) ------
__global__ __launch_bounds__(256) void mlp_fused(
    const unsigned short* __restrict__ xn2,
    const unsigned short* __restrict__ w1T, const float* __restrict__ b1,
    const unsigned short* __restrict__ w2T, const float* __restrict__ b2,
    float* __restrict__ io){                   // d_out: in x2 (NCHW), out final
  __shared__ char smem[64 * 392 * 2];          // 50176 B, aliased
  unsigned short (*sH)[392] = (unsigned short(*)[392])smem;
  float (*sY)[101] = (float(*)[101])smem;
  int tid = threadIdx.x, blk = blockIdx.x;
  int bi = blk / (HW / 64);
  int pos0 = (blk - bi * (HW / 64)) * 64;
  size_t tokBase = (size_t)bi * HW + pos0;
  int wv = tid >> 6, lane = tid & 63;
  int r = lane & 15, kg = (lane >> 4) * 8;
  // phase 1: h = gelu(xn2 @ w1T + b1); wave -> 6 ntiles, 4 mtiles
  int nb = wv * 6;
  f32x4 acc[4][6];
  #pragma unroll
  for (int m = 0; m < 4; ++m)
    #pragma unroll
    for (int j = 0; j < 6; ++j) acc[m][j] = (f32x4){0.f,0.f,0.f,0.f};
  #pragma unroll
  for (int k0 = 0; k0 < 96; k0 += 32){
    bf16x8 a[4];
    #pragma unroll
    for (int m = 0; m < 4; ++m)
      a[m] = *(const bf16x8*)(xn2 + (tokBase + m * 16 + r) * CB + kg + k0);
    #pragma unroll
    for (int j = 0; j < 6; ++j){
      bf16x8 b = *(const bf16x8*)(w1T + ((nb + j) * 16 + r) * CB + kg + k0);
      #pragma unroll
      for (int m = 0; m < 4; ++m)
        acc[m][j] = __builtin_amdgcn_mfma_f32_16x16x32_bf16(a[m], b, acc[m][j], 0, 0, 0);
    }
  }
  int orow = (lane >> 4) * 4;
  #pragma unroll
  for (int j = 0; j < 6; ++j){
    int col = (nb + j) * 16 + r;
    float bs = b1[col];
    #pragma unroll
    for (int m = 0; m < 4; ++m){
      #pragma unroll
      for (int i = 0; i < 4; ++i){
        float v = acc[m][j][i] + bs;
        v = 0.5f * v * (1.f + erff(v * 0.70710678118654752f));
        sH[m * 16 + orow + i][col] = f2bf(v);
      }
    }
  }
  __syncthreads();
  // phase 2: y2 = h @ w2T + b2; wave -> 2 mtiles x 3 ntiles
  int mb = (wv & 1) * 2, n2b = (wv >> 1) * 3;
  f32x4 acc2[2][3];
  #pragma unroll
  for (int m = 0; m < 2; ++m)
    #pragma unroll
    for (int j = 0; j < 3; ++j) acc2[m][j] = (f32x4){0.f,0.f,0.f,0.f};
  #pragma unroll
  for (int ks = 0; ks < 12; ++ks){
    int k0 = ks * 32;
    bf16x8 a2[2];
    #pragma unroll
    for (int m = 0; m < 2; ++m)
      a2[m] = *(const bf16x8*)&sH[(mb + m) * 16 + r][k0 + kg];
    #pragma unroll
    for (int j = 0; j < 3; ++j){
      bf16x8 b = *(const bf16x8*)(w2T + ((n2b + j) * 16 + r) * HIDDEN + k0 + kg);
      #pragma unroll
      for (int m = 0; m < 2; ++m)
        acc2[m][j] = __builtin_amdgcn_mfma_f32_16x16x32_bf16(a2[m], b, acc2[m][j], 0, 0, 0);
    }
  }
  __syncthreads();   // done reading sH; sY aliases it
  #pragma unroll
  for (int j = 0; j < 3; ++j){
    int col = (n2b + j) * 16 + r;
    float bs = b2[col];
    #pragma unroll
    for (int m = 0; m < 2; ++m){
      #pragma unroll
      for (int i = 0; i < 4; ++i)
        sY[(mb + m) * 16 + orow + i][col] = acc2[m][j][i] + bs;
    }
  }
  __syncthreads();
  float* ob = io + (size_t)bi * CB * HW + pos0;
  for (int it = 0; it < 24; ++it){
    int idx = it * 256 + tid;
    int c = idx >> 6, p = idx & 63;
    size_t a = (size_t)c * HW + p;
    ob[a] = sY[p][c] + ob[a];
  }
}

extern "C" void kernel_launch(void* const* d_in, const int* in_sizes, int n_in,
                              void* d_out, int out_size, void* d_ws, size_t ws_size,
                              hipStream_t stream){
  const float* x        = (const float*)d_in[0];
  const float* n1g      = (const float*)d_in[1];
  const float* n1b      = (const float*)d_in[2];
  const float* qkv_w    = (const float*)d_in[3];
  const float* qkv_b    = (const float*)d_in[4];
  const float* proj_w   = (const float*)d_in[5];
  const float* proj_b   = (const float*)d_in[6];
  const float* rel_bias = (const float*)d_in[7];
  const float* n2g      = (const float*)d_in[8];
  const float* n2b      = (const float*)d_in[9];
  const float* w1       = (const float*)d_in[10];
  const float* b1       = (const float*)d_in[11];
  const float* w2       = (const float*)d_in[12];
  const float* b2       = (const float*)d_in[13];
  const int* rel_index  = (const int*)d_in[14];
  float* outp = (float*)d_out;

  char* ws = (char*)d_ws;
  unsigned short* qkvT  = (unsigned short*)ws;          // 288x96
  unsigned short* projT = qkvT + 288 * 96;              // 96x96
  unsigned short* w1T   = projT + 96 * 96;              // 384x96
  unsigned short* w2T   = w1T + 384 * 96;               // 96x384
  unsigned short* xn    = (unsigned short*)(ws + 221184); // (tok,96) bf16, 38.5 MB

  wprep<<<dim3(108), 256, 0, stream>>>(qkv_w, qkvT, 96, 288);
  wprep<<<dim3(36),  256, 0, stream>>>(proj_w, projT, 96, 96);
  wprep<<<dim3(144), 256, 0, stream>>>(w1, w1T, 96, 384);
  wprep<<<dim3(144), 256, 0, stream>>>(w2, w2T, 384, 96);

  ln_first  <<<dim3(NTOK / 64), 256, 0, stream>>>(x, n1g, n1b, xn);
  attn_fused<<<dim3(NWIN),      256, 0, stream>>>(xn, qkvT, qkv_b, rel_bias, rel_index);
  proj_ln2  <<<dim3(NTOK / 64), 256, 0, stream>>>(xn, projT, proj_b, x, n2g, n2b, outp);
  mlp_fused <<<dim3(NTOK / 64), 256, 0, stream>>>(xn, w1T, b1, w2T, b2, outp);
}

// Round 3
// 341.387 us; speedup vs baseline: 1.7713x; 1.7713x over previous
//
#include <hip/hip_runtime.h>
#include <hip/hip_bf16.h>
#include <cstdint>

#define HW 50176
#define CB 96
#define BATCH 4
#define NTOK (BATCH*HW)
#define NWIN 4096
#define HIDDEN 384

typedef __attribute__((ext_vector_type(8))) short bf16x8;
typedef __attribute__((ext_vector_type(4))) float f32x4;

__device__ inline unsigned short f2bf(float f){
  union { float f; unsigned u; } x; x.f = f;
  unsigned r = x.u + 0x7fffu + ((x.u >> 16) & 1u);
  return (unsigned short)(r >> 16);
}
__device__ inline float bf2f(unsigned short h){
  union { unsigned u; float f; } x; x.u = ((unsigned)h) << 16; return x.f;
}
__device__ inline unsigned pack2(float a, float b){
  return (unsigned)f2bf(a) | ((unsigned)f2bf(b) << 16);
}

// ---------------- weight prep: fp32 (K,N) -> bf16 transposed (N,K) ----------
__global__ void wprep(const float* __restrict__ src, unsigned short* __restrict__ dst,
                      int K, int N){
  int id = blockIdx.x * 256 + threadIdx.x;
  if (id >= K * N) return;
  int n = id / K, k = id - n * K;
  dst[id] = f2bf(src[k * N + n]);
}

// ---------------- bias prep: biasT[h][k>>2][q][k&3] = bias(q,k,h) ----------
// S'[k][q] accumulator init: lane loads float4 over i (k = 16j+4g+i).
__global__ void biasprep(const float* __restrict__ rb, const int* __restrict__ ri,
                         float* __restrict__ bt){
  int t = blockIdx.x * 256 + threadIdx.x;      // 3*64*64
  if (t >= 3 * 64 * 64) return;
  int h = t >> 12, k = (t >> 6) & 63, q = t & 63;
  float v = 0.f;
  if (k < 49 && q < 49) v = rb[ri[q * 49 + k] * 3 + h];
  bt[((h * 16 + (k >> 2)) * 64 + q) * 4 + (k & 3)] = v;
}

// ---------------- LN1: NCHW -> token-major bf16, layernorm over C ----------
__global__ __launch_bounds__(256) void ln_first(const float* __restrict__ x,
    const float* __restrict__ g, const float* __restrict__ bta,
    unsigned short* __restrict__ out){
  __shared__ float s[64][97];
  int tid = threadIdx.x;
  int blk = blockIdx.x;
  int bi = blk / (HW / 64);
  int pos0 = (blk - bi * (HW / 64)) * 64;
  const float* xb = x + (size_t)bi * CB * HW + pos0;
  for (int it = 0; it < 24; ++it){
    int idx = it * 256 + tid;
    int c = idx >> 6, p = idx & 63;
    s[p][c] = xb[(size_t)c * HW + p];
  }
  __syncthreads();
  int p = tid >> 2, part = tid & 3;
  float sum = 0.f, sq = 0.f;
  #pragma unroll
  for (int j = 0; j < 24; ++j){ float v = s[p][part * 24 + j]; sum += v; sq += v * v; }
  sum += __shfl_xor(sum, 1); sq += __shfl_xor(sq, 1);
  sum += __shfl_xor(sum, 2); sq += __shfl_xor(sq, 2);
  float mean = sum * (1.f / 96.f);
  float var  = sq * (1.f / 96.f) - mean * mean;
  float rs = rsqrtf(var + 1e-5f);
  size_t tok = (size_t)bi * HW + pos0 + p;
  float vv[24];
  #pragma unroll
  for (int j = 0; j < 24; ++j){
    int c = part * 24 + j;
    vv[j] = (s[p][c] - mean) * rs * g[c] + bta[c];
  }
  unsigned pw[12];
  #pragma unroll
  for (int j = 0; j < 12; ++j) pw[j] = pack2(vv[2 * j], vv[2 * j + 1]);
  uint4* dst = (uint4*)(out + tok * CB + part * 24);
  dst[0] = make_uint4(pw[0], pw[1], pw[2], pw[3]);
  dst[1] = make_uint4(pw[4], pw[5], pw[6], pw[7]);
  dst[2] = make_uint4(pw[8], pw[9], pw[10], pw[11]);
}

// ---------------- fused qkv-GEMM + MFMA window attention (in-place xn) -----
// block = 1 window (256 thr, 4 waves). Swapped QK^T: S'[k][q]=mfma(K,Q);
// lane owns q = 16*wave + (lane&15), holds 16 k-slots -> shfl softmax.
__global__ __launch_bounds__(256) void attn_fused(
    unsigned short* __restrict__ xn,           // in: xn1, out: attn_out
    const unsigned short* __restrict__ qkvT,   // (288,96) bf16
    const float* __restrict__ qkv_b,
    const float* __restrict__ biasT){          // [3][16][64][4] fp32
  __shared__ unsigned short sQ[64][104];       // bf16, scale folded, pad rows 0
  __shared__ unsigned short sK[64][104];
  __shared__ unsigned short sVT[3][32][72];    // V^T per head
  __shared__ unsigned short sP[64][72];        // P[q][k], normalized bf16
  int tid = threadIdx.x;
  int wid = blockIdx.x;
  int bi = wid >> 10;
  int wy = (wid & 1023) >> 5, wx = wid & 31;
  int rowbase = bi * HW + (wy * 7) * 224 + wx * 7;

  int wv = tid >> 6, lane = tid & 63;
  int r = lane & 15, g = lane >> 4;
  int kg = g * 8;
  // ---- qkv GEMM: wave wv handles ntiles {0-4,5-9,10-13,14-17} ----
  int nbase = (wv < 2) ? wv * 5 : 10 + (wv - 2) * 4;
  int ncnt  = (wv < 2) ? 5 : 4;
  int arow[4];
  #pragma unroll
  for (int m = 0; m < 4; ++m){
    int rr = m * 16 + r; if (rr > 48) rr = 48;
    arow[m] = rowbase + (rr / 7) * 224 + (rr % 7);
  }
  f32x4 acc[4][5];
  #pragma unroll
  for (int m = 0; m < 4; ++m)
    #pragma unroll
    for (int j = 0; j < 5; ++j) acc[m][j] = (f32x4){0.f,0.f,0.f,0.f};
  #pragma unroll
  for (int k0 = 0; k0 < 96; k0 += 32){
    bf16x8 a[4];
    #pragma unroll
    for (int m = 0; m < 4; ++m)
      a[m] = *(const bf16x8*)(xn + (size_t)arow[m] * CB + kg + k0);
    #pragma unroll
    for (int j = 0; j < 5; ++j){
      if (j < ncnt){
        int nt = nbase + j;
        bf16x8 b = *(const bf16x8*)(qkvT + (nt * 16 + r) * CB + kg + k0);
        #pragma unroll
        for (int m = 0; m < 4; ++m)
          acc[m][j] = __builtin_amdgcn_mfma_f32_16x16x32_bf16(a[m], b, acc[m][j], 0, 0, 0);
      }
    }
  }
  int orow = g * 4;
  #pragma unroll
  for (int j = 0; j < 5; ++j){
    if (j < ncnt){
      int nt = nbase + j;
      int col = nt * 16 + r;
      float bs = qkv_b[col];
      #pragma unroll
      for (int m = 0; m < 4; ++m){
        #pragma unroll
        for (int i = 0; i < 4; ++i){
          int row = m * 16 + orow + i;
          float v = (row < 49) ? acc[m][j][i] + bs : 0.f;
          if (col < 96)       sQ[row][col] = f2bf(v * 0.17677669529663687f);
          else if (col < 192) sK[row][col - 96] = f2bf(v);
          else { int cc = col - 192; sVT[cc >> 5][cc & 31][row] = f2bf(v); }
        }
      }
    }
  }
  __syncthreads();

  // ---- attention: all 4 waves; wave owns q-tile wv ----
  int qrow = 16 * wv + r;                      // this lane's query (col of S')
  int qq = 16 * wv + 4 * g;                    // O-epilogue base row
  #pragma unroll
  for (int h = 0; h < 3; ++h){
    // S' = K @ Q^T + bias : 4 MFMAs (k-tiles), K-dim = 32
    bf16x8 bq = *(const bf16x8*)&sQ[qrow][h * 32 + kg];
    f32x4 sacc[4];
    #pragma unroll
    for (int j = 0; j < 4; ++j)
      sacc[j] = *(const f32x4*)&biasT[(((h * 16) + 4 * j + g) * 64 + qrow) * 4];
    #pragma unroll
    for (int j = 0; j < 4; ++j){
      bf16x8 ak = *(const bf16x8*)&sK[16 * j + r][h * 32 + kg];
      sacc[j] = __builtin_amdgcn_mfma_f32_16x16x32_bf16(ak, bq, sacc[j], 0, 0, 0);
    }
    // softmax over k (16 local slots + xor16/32), mask k>48
    float mx = -1e30f;
    #pragma unroll
    for (int j = 0; j < 4; ++j)
      #pragma unroll
      for (int i = 0; i < 4; ++i){
        int k = 16 * j + 4 * g + i;
        if (k <= 48) mx = fmaxf(mx, sacc[j][i]);
      }
    mx = fmaxf(mx, __shfl_xor(mx, 16));
    mx = fmaxf(mx, __shfl_xor(mx, 32));
    float p[4][4], sum = 0.f;
    #pragma unroll
    for (int j = 0; j < 4; ++j)
      #pragma unroll
      for (int i = 0; i < 4; ++i){
        int k = 16 * j + 4 * g + i;
        float pv = (k <= 48) ? __expf(sacc[j][i] - mx) : 0.f;
        p[j][i] = pv; sum += pv;
      }
    sum += __shfl_xor(sum, 16);
    sum += __shfl_xor(sum, 32);
    float inv = 1.f / sum;
    #pragma unroll
    for (int j = 0; j < 4; ++j){
      uint2 w2;
      w2.x = pack2(p[j][0] * inv, p[j][1] * inv);
      w2.y = pack2(p[j][2] * inv, p[j][3] * inv);
      *(uint2*)&sP[qrow][16 * j + 4 * g] = w2;
    }
    __syncthreads();                           // P visible across lanes
    // O = P @ V : 2 n-tiles x 2 k-steps
    f32x4 oacc[2];
    oacc[0] = (f32x4){0.f,0.f,0.f,0.f};
    oacc[1] = (f32x4){0.f,0.f,0.f,0.f};
    #pragma unroll
    for (int k0 = 0; k0 < 64; k0 += 32){
      bf16x8 ap = *(const bf16x8*)&sP[16 * wv + r][k0 + kg];
      #pragma unroll
      for (int n = 0; n < 2; ++n){
        bf16x8 bv = *(const bf16x8*)&sVT[h][n * 16 + r][k0 + kg];
        oacc[n] = __builtin_amdgcn_mfma_f32_16x16x32_bf16(ap, bv, oacc[n], 0, 0, 0);
      }
    }
    // store O rows (q<49) as bf16 scalars (16-lane/32B coalesced)
    #pragma unroll
    for (int i = 0; i < 4; ++i){
      int q = qq + i;
      if (q < 49){
        int tok = rowbase + (q / 7) * 224 + (q % 7);
        unsigned short* dst = xn + (size_t)tok * CB + h * 32 + r;
        dst[0]  = f2bf(oacc[0][i]);
        dst[16] = f2bf(oacc[1][i]);
      }
    }
    __syncthreads();                           // WAR: next head rewrites sP
  }
}

// ---------------- proj GEMM + residual + LN2 (in-place att->xn2) -----------
__global__ __launch_bounds__(256) void proj_ln2(
    unsigned short* __restrict__ att,          // in: attn_out, out: xn2
    const unsigned short* __restrict__ projT, const float* __restrict__ proj_b,
    const float* __restrict__ x, const float* __restrict__ g,
    const float* __restrict__ bta,
    float* __restrict__ x2out){                // d_out, NCHW
  __shared__ float sY[64][101];
  int tid = threadIdx.x, blk = blockIdx.x;
  int bi = blk / (HW / 64);
  int pos0 = (blk - bi * (HW / 64)) * 64;
  size_t tokBase = (size_t)bi * HW + pos0;
  int wv = tid >> 6, lane = tid & 63;
  int r = lane & 15, kg = (lane >> 4) * 8;
  const unsigned short* Arow = att + (tokBase + wv * 16 + r) * CB + kg;
  f32x4 acc[6];
  #pragma unroll
  for (int j = 0; j < 6; ++j) acc[j] = (f32x4){0.f,0.f,0.f,0.f};
  #pragma unroll
  for (int k0 = 0; k0 < 96; k0 += 32){
    bf16x8 a = *(const bf16x8*)(Arow + k0);
    #pragma unroll
    for (int j = 0; j < 6; ++j){
      bf16x8 b = *(const bf16x8*)(projT + (j * 16 + r) * CB + kg + k0);
      acc[j] = __builtin_amdgcn_mfma_f32_16x16x32_bf16(a, b, acc[j], 0, 0, 0);
    }
  }
  int orow = wv * 16 + (lane >> 4) * 4;
  #pragma unroll
  for (int j = 0; j < 6; ++j){
    int col = j * 16 + r;
    float bs = proj_b[col];
    #pragma unroll
    for (int i = 0; i < 4; ++i) sY[orow + i][col] = acc[j][i] + bs;
  }
  __syncthreads();
  const float* xb = x + (size_t)bi * CB * HW + pos0;
  float* ob = x2out + (size_t)bi * CB * HW + pos0;
  for (int it = 0; it < 24; ++it){
    int idx = it * 256 + tid;
    int c = idx >> 6, p = idx & 63;
    float v = sY[p][c] + xb[(size_t)c * HW + p];
    ob[(size_t)c * HW + p] = v;
    sY[p][c] = v;
  }
  __syncthreads();
  int p = tid >> 2, part = tid & 3;
  float sum = 0.f, sq = 0.f;
  #pragma unroll
  for (int j = 0; j < 24; ++j){ float v = sY[p][part * 24 + j]; sum += v; sq += v * v; }
  sum += __shfl_xor(sum, 1); sq += __shfl_xor(sq, 1);
  sum += __shfl_xor(sum, 2); sq += __shfl_xor(sq, 2);
  float mean = sum * (1.f / 96.f);
  float var  = sq * (1.f / 96.f) - mean * mean;
  float rs = rsqrtf(var + 1e-5f);
  float vv[24];
  #pragma unroll
  for (int j = 0; j < 24; ++j){
    int c = part * 24 + j;
    vv[j] = (sY[p][c] - mean) * rs * g[c] + bta[c];
  }
  unsigned pw[12];
  #pragma unroll
  for (int j = 0; j < 12; ++j) pw[j] = pack2(vv[2 * j], vv[2 * j + 1]);
  uint4* dst = (uint4*)(att + (tokBase + p) * CB + part * 24);
  dst[0] = make_uint4(pw[0], pw[1], pw[2], pw[3]);
  dst[1] = make_uint4(pw[4], pw[5], pw[6], pw[7]);
  dst[2] = make_uint4(pw[8], pw[9], pw[10], pw[11]);
}

// ---------------- fused MLP: gelu(xn2@w1+b1)@w2+b2 + x2 -> out (NCHW) ------
__global__ __launch_bounds__(256) void mlp_fused(
    const unsigned short* __restrict__ xn2,
    const unsigned short* __restrict__ w1T, const float* __restrict__ b1,
    const unsigned short* __restrict__ w2T, const float* __restrict__ b2,
    float* __restrict__ io){                   // d_out: in x2 (NCHW), out final
  __shared__ char smem[64 * 392 * 2];          // 50176 B, aliased
  unsigned short (*sH)[392] = (unsigned short(*)[392])smem;
  float (*sY)[101] = (float(*)[101])smem;
  int tid = threadIdx.x, blk = blockIdx.x;
  int bi = blk / (HW / 64);
  int pos0 = (blk - bi * (HW / 64)) * 64;
  size_t tokBase = (size_t)bi * HW + pos0;
  int wv = tid >> 6, lane = tid & 63;
  int r = lane & 15, kg = (lane >> 4) * 8;
  int nb = wv * 6;
  f32x4 acc[4][6];
  #pragma unroll
  for (int m = 0; m < 4; ++m)
    #pragma unroll
    for (int j = 0; j < 6; ++j) acc[m][j] = (f32x4){0.f,0.f,0.f,0.f};
  #pragma unroll
  for (int k0 = 0; k0 < 96; k0 += 32){
    bf16x8 a[4];
    #pragma unroll
    for (int m = 0; m < 4; ++m)
      a[m] = *(const bf16x8*)(xn2 + (tokBase + m * 16 + r) * CB + kg + k0);
    #pragma unroll
    for (int j = 0; j < 6; ++j){
      bf16x8 b = *(const bf16x8*)(w1T + ((nb + j) * 16 + r) * CB + kg + k0);
      #pragma unroll
      for (int m = 0; m < 4; ++m)
        acc[m][j] = __builtin_amdgcn_mfma_f32_16x16x32_bf16(a[m], b, acc[m][j], 0, 0, 0);
    }
  }
  int orow = (lane >> 4) * 4;
  #pragma unroll
  for (int j = 0; j < 6; ++j){
    int col = (nb + j) * 16 + r;
    float bs = b1[col];
    #pragma unroll
    for (int m = 0; m < 4; ++m){
      #pragma unroll
      for (int i = 0; i < 4; ++i){
        float v = acc[m][j][i] + bs;
        v = 0.5f * v * (1.f + erff(v * 0.70710678118654752f));
        sH[m * 16 + orow + i][col] = f2bf(v);
      }
    }
  }
  __syncthreads();
  int mb = (wv & 1) * 2, n2b = (wv >> 1) * 3;
  f32x4 acc2[2][3];
  #pragma unroll
  for (int m = 0; m < 2; ++m)
    #pragma unroll
    for (int j = 0; j < 3; ++j) acc2[m][j] = (f32x4){0.f,0.f,0.f,0.f};
  #pragma unroll
  for (int ks = 0; ks < 12; ++ks){
    int k0 = ks * 32;
    bf16x8 a2[2];
    #pragma unroll
    for (int m = 0; m < 2; ++m)
      a2[m] = *(const bf16x8*)&sH[(mb + m) * 16 + r][k0 + kg];
    #pragma unroll
    for (int j = 0; j < 3; ++j){
      bf16x8 b = *(const bf16x8*)(w2T + ((n2b + j) * 16 + r) * HIDDEN + k0 + kg);
      #pragma unroll
      for (int m = 0; m < 2; ++m)
        acc2[m][j] = __builtin_amdgcn_mfma_f32_16x16x32_bf16(a2[m], b, acc2[m][j], 0, 0, 0);
    }
  }
  __syncthreads();
  #pragma unroll
  for (int j = 0; j < 3; ++j){
    int col = (n2b + j) * 16 + r;
    float bs = b2[col];
    #pragma unroll
    for (int m = 0; m < 2; ++m){
      #pragma unroll
      for (int i = 0; i < 4; ++i)
        sY[(mb + m) * 16 + orow + i][col] = acc2[m][j][i] + bs;
    }
  }
  __syncthreads();
  float* ob = io + (size_t)bi * CB * HW + pos0;
  for (int it = 0; it < 24; ++it){
    int idx = it * 256 + tid;
    int c = idx >> 6, p = idx & 63;
    size_t a = (size_t)c * HW + p;
    ob[a] = sY[p][c] + ob[a];
  }
}

extern "C" void kernel_launch(void* const* d_in, const int* in_sizes, int n_in,
                              void* d_out, int out_size, void* d_ws, size_t ws_size,
                              hipStream_t stream){
  const float* x        = (const float*)d_in[0];
  const float* n1g      = (const float*)d_in[1];
  const float* n1b      = (const float*)d_in[2];
  const float* qkv_w    = (const float*)d_in[3];
  const float* qkv_b    = (const float*)d_in[4];
  const float* proj_w   = (const float*)d_in[5];
  const float* proj_b   = (const float*)d_in[6];
  const float* rel_bias = (const float*)d_in[7];
  const float* n2g      = (const float*)d_in[8];
  const float* n2b      = (const float*)d_in[9];
  const float* w1       = (const float*)d_in[10];
  const float* b1       = (const float*)d_in[11];
  const float* w2       = (const float*)d_in[12];
  const float* b2       = (const float*)d_in[13];
  const int* rel_index  = (const int*)d_in[14];
  float* outp = (float*)d_out;

  char* ws = (char*)d_ws;
  unsigned short* qkvT  = (unsigned short*)ws;            // 288x96
  unsigned short* projT = qkvT + 288 * 96;                // 96x96
  unsigned short* w1T   = projT + 96 * 96;                // 384x96
  unsigned short* w2T   = w1T + 384 * 96;                 // 96x384
  float* biasT          = (float*)(ws + 221184);          // [3][16][64][4]
  unsigned short* xn    = (unsigned short*)(ws + 221184 + 49152);

  wprep<<<dim3(108), 256, 0, stream>>>(qkv_w, qkvT, 96, 288);
  wprep<<<dim3(36),  256, 0, stream>>>(proj_w, projT, 96, 96);
  wprep<<<dim3(144), 256, 0, stream>>>(w1, w1T, 96, 384);
  wprep<<<dim3(144), 256, 0, stream>>>(w2, w2T, 384, 96);
  biasprep<<<dim3(48), 256, 0, stream>>>(rel_bias, rel_index, biasT);

  ln_first  <<<dim3(NTOK / 64), 256, 0, stream>>>(x, n1g, n1b, xn);
  attn_fused<<<dim3(NWIN),      256, 0, stream>>>(xn, qkvT, qkv_b, biasT);
  proj_ln2  <<<dim3(NTOK / 64), 256, 0, stream>>>(xn, projT, proj_b, x, n2g, n2b, outp);
  mlp_fused <<<dim3(NTOK / 64), 256, 0, stream>>>(xn, w1T, b1, w2T, b2, outp);
}